// Round 7
// baseline (540.341 us; speedup 1.0000x reference)
//
#include <hip/hip_runtime.h>
#include <hip/hip_bf16.h>

typedef __attribute__((ext_vector_type(4))) float f32x4;
typedef __attribute__((ext_vector_type(8))) short s16x8;
typedef __attribute__((ext_vector_type(4))) short s16x4;
typedef __attribute__((ext_vector_type(4))) unsigned int u32x4;

#define MFMA16(A, B, C) __builtin_amdgcn_mfma_f32_16x16x32_bf16((A), (B), (C), 0, 0, 0)

#define GLDS16(gsrc, ldst) __builtin_amdgcn_global_load_lds(                   \
    (const __attribute__((address_space(1))) void*)(gsrc),                    \
    (__attribute__((address_space(3))) void*)(ldst), 16, 0, 0)

__device__ __forceinline__ ushort f2bf(float f) {
    __hip_bfloat16 h = __float2bfloat16(f);
    return *reinterpret_cast<ushort*>(&h);
}

// branchless exact GELU via Abramowitz-Stegun 7.1.26 erf (|err| <= 1.5e-7)
__device__ __forceinline__ float gelu_exact(float x) {
    float z = 0.70710678118f * x;
    float az = fabsf(z);
    float t = 1.0f / fmaf(0.3275911f, az, 1.0f);
    float poly = t * (0.254829592f + t * (-0.284496736f + t * (1.421413741f +
                 t * (-1.453152027f + t * 1.061405429f))));
    float e = __expf(-az * az);
    float erfv = copysignf(1.0f - poly * e, z);
    return 0.5f * x * (1.0f + erfv);
}

// ---------------- convert fp32 -> bf16 (vectorized x4) ----------------
__global__ void k_cvt(const float* __restrict__ in, ushort* __restrict__ out, int n) {
    int i = (blockIdx.x * 256 + threadIdx.x) * 4;
    if (i + 3 >= n) return;
    float4 v = *(const float4*)(in + i);
    ushort4 o;
    o.x = f2bf(v.x); o.y = f2bf(v.y); o.z = f2bf(v.z); o.w = f2bf(v.w);
    *(ushort4*)(out + i) = o;
}

// ---------------- transpose weight [K,N] f32 -> [N,K] bf16 ----------------
__global__ void k_twT(const float* __restrict__ w, ushort* __restrict__ wt, int K, int N) {
    __shared__ float tile[32][33];
    int k0 = blockIdx.x * 32, n0 = blockIdx.y * 32;
    int tx = threadIdx.x & 31, ty = threadIdx.x >> 5;   // 32 x 8
    #pragma unroll
    for (int i = ty; i < 32; i += 8)
        tile[i][tx] = w[(size_t)(k0 + i) * N + n0 + tx];
    __syncthreads();
    #pragma unroll
    for (int i = ty; i < 32; i += 8)
        wt[(size_t)(n0 + i) * K + k0 + tx] = f2bf(tile[tx][i]);
}

// ---------------- zero chunk 9 of Vt (keys 288..319 region) ----------------
// Vt tiled layout: [(b*8+h)][kc(10)][v(256)][k32(32)] ushort (slot-swizzled)
__global__ void k_zeroV9(ushort* __restrict__ Vt) {
    int i = (blockIdx.x * 256 + threadIdx.x) * 8;   // < 512*8192
    int bh = i >> 13, within = i & 8191;
    s16x8 z = {0, 0, 0, 0, 0, 0, 0, 0};
    *(s16x8*)(Vt + ((size_t)bh * 10 + 9) * 8192 + within) = z;
}

// ---------------- GEMM: A[M,K]bf16 @ BT[N,K]bf16^T + bias ----------------
// m97 structure: global_load_lds width-16 staging, linear LDS [128][32].
// Grid: 1D, 152*GY blocks (GX=150 padded to 152=19*8 for XCD chunking).
// OUT=0: bf16 [M,N].  OUT=1: bf16 tiled+swizzled Vt.  OUT=2: f32 +bias+resid.
template <int OUT>
__global__ __launch_bounds__(256) void k_gemm(const ushort* __restrict__ A,
                                              const ushort* __restrict__ BT,
                                              const float* __restrict__ bias,
                                              const float* __restrict__ resid,
                                              void* __restrict__ outp,
                                              int N, int K, int GY) {
    __shared__ __align__(16) ushort As[128][32];
    __shared__ __align__(16) ushort Bs[128][32];
    int id = blockIdx.x;
    int xcd = id & 7, s = id >> 3;          // s in [0, 19*GY)
    int mxl = s / GY, ny = s - mxl * GY;
    int mx = xcd * 19 + mxl;
    if (mx >= 150) return;
    int m0 = mx * 128, n0 = ny * 128;

    int t = threadIdx.x, l = t & 63, w = t >> 6;
    int wm = (w >> 1) * 64, wn = (w & 1) * 64;
    int lr = l & 15, lg = l >> 4;
    ushort* AsF = &As[0][0];
    ushort* BsF = &Bs[0][0];

    f32x4 acc[4][4];
    #pragma unroll
    for (int i = 0; i < 4; ++i)
        #pragma unroll
        for (int j = 0; j < 4; ++j)
            acc[i][j] = (f32x4){0.f, 0.f, 0.f, 0.f};

    for (int k0 = 0; k0 < K; k0 += 32) {
        #pragma unroll
        for (int c = 0; c < 2; ++c) {
            int cb = w * 128 + c * 64;          // wave-uniform chunk base
            int ch = cb + l;
            int row = ch >> 2, col = (ch & 3) * 8;
            GLDS16(A + (size_t)(m0 + row) * K + k0 + col, AsF + (size_t)cb * 8);
            GLDS16(BT + (size_t)(n0 + row) * K + k0 + col, BsF + (size_t)cb * 8);
        }
        __syncthreads();
        s16x8 af[4], bfr[4];
        #pragma unroll
        for (int i = 0; i < 4; ++i) af[i] = *(const s16x8*)(&As[wm + i * 16 + lr][lg * 8]);
        #pragma unroll
        for (int j = 0; j < 4; ++j) bfr[j] = *(const s16x8*)(&Bs[wn + j * 16 + lr][lg * 8]);
        #pragma unroll
        for (int i = 0; i < 4; ++i)
            #pragma unroll
            for (int j = 0; j < 4; ++j)
                acc[i][j] = MFMA16(af[i], bfr[j], acc[i][j]);
        __syncthreads();
    }

    if (OUT == 0) {
        ushort* out = (ushort*)outp;
        #pragma unroll
        for (int i = 0; i < 4; ++i)
            #pragma unroll
            for (int j = 0; j < 4; ++j) {
                int col = n0 + wn + j * 16 + lr;
                float bv = bias[col];
                #pragma unroll
                for (int r = 0; r < 4; ++r) {
                    int row = m0 + wm + i * 16 + lg * 4 + r;
                    out[(size_t)row * N + col] = f2bf(acc[i][j][r] + bv);
                }
            }
    } else if (OUT == 1) {
        ushort* Vt = (ushort*)outp;
        #pragma unroll
        for (int i = 0; i < 4; ++i)
            #pragma unroll
            for (int j = 0; j < 4; ++j) {
                int col = n0 + wn + j * 16 + lr;
                float bv = bias[col];
                int hh = col >> 8, v = col & 255;
                #pragma unroll
                for (int r = 0; r < 4; ++r) {
                    int row = m0 + wm + i * 16 + lg * 4 + r;
                    int bb = row / 300, key = row - bb * 300;
                    int ck = key >> 5, kk = key & 31;
                    int sl = (kk >> 3) ^ ((v >> 1) & 3);    // 16B-slot swizzle
                    size_t addr = (((size_t)(bb * 8 + hh) * 10 + ck) * 8192)
                                  + v * 32 + sl * 8 + (kk & 7);
                    Vt[addr] = f2bf(acc[i][j][r] + bv);
                }
            }
    } else {
        float* out = (float*)outp;
        #pragma unroll
        for (int i = 0; i < 4; ++i)
            #pragma unroll
            for (int j = 0; j < 4; ++j) {
                int col = n0 + wn + j * 16 + lr;
                float bv = bias[col];
                #pragma unroll
                for (int r = 0; r < 4; ++r) {
                    int row = m0 + wm + i * 16 + lg * 4 + r;
                    size_t idx = (size_t)row * N + col;
                    out[idx] = acc[i][j][r] + bv + resid[idx];
                }
            }
    }
}

// ---------------- fused attention ----------------
// Streaming softmax WITHOUT max-subtraction (|x|<=~7 -> exp<=~1100, f32-safe;
// softmax is shift-invariant so result matches reference). P stays in regs
// as unnormalized exp (bf16); 1/sum folded into the PV epilogue.
// Forced <=128 regs/wave for occupancy. V double-buffer glds staging.
__global__ __launch_bounds__(256, 4) void k_attn(const ushort* __restrict__ qf_bf,
                                                 const ushort* __restrict__ G_bf,
                                                 const ushort* __restrict__ Vt,
                                                 const float* __restrict__ wb,
                                                 const float* __restrict__ bias,
                                                 ushort* __restrict__ O) {
    __shared__ __align__(16) ushort Vs[2][8192];   // 32,768 B
    int id = blockIdx.x;
    int xcd = id & 7, s = id >> 3;        // s in [0,320)
    int h = s / 40; int r2 = s - h * 40;
    int bi = r2 / 5, qt = r2 - bi * 5;
    int b = xcd * 8 + bi;

    int t = threadIdx.x, l = t & 63, w = t >> 6;
    int lr = l & 15, lg = l >> 4;

    const ushort* vchunk = Vt + (size_t)(b * 8 + h) * 81920;   // 10 chunks x 8192

    // stage chunk 0 (async, no VGPRs) -- lands during scores phase
    #pragma unroll
    for (int c = 0; c < 4; ++c)
        GLDS16(vchunk + w * 2048 + c * 512 + l * 8, &Vs[0][w * 2048 + c * 512]);

    // Q fragment (B operand): col = q = lane&15
    int qr = min(qt * 64 + w * 16 + lr, 299);
    const ushort* qp = qf_bf + ((size_t)(b * 300 + qr)) * 512 + h * 64 + lg * 8;
    s16x8 q0 = *(const s16x8*)(qp);
    s16x8 q1 = *(const s16x8*)(qp + 32);

    // ---- scores^T, gelu, exp streamed; pk[kt] = bf16 exp pairs ----
    unsigned int pk[20][2];
    float ssum = 0.f;
    #pragma unroll
    for (int kt = 0; kt < 19; ++kt) {
        int key = kt * 16 + lr;
        int kcl = min(key, 299);
        const ushort* gp = G_bf + ((size_t)(b * 300 + kcl)) * 512 + h * 64 + lg * 8;
        s16x8 g0 = *(const s16x8*)(gp);
        s16x8 g1 = *(const s16x8*)(gp + 32);
        f32x4 a = (f32x4){0.f, 0.f, 0.f, 0.f};
        a = MFMA16(g0, q0, a);
        a = MFMA16(g1, q1, a);
        int k0 = kt * 16 + lg * 4;
        int k0c = min(k0, 296);
        size_t bidx = ((size_t)h * 300 + qr) * 300 + k0c;
        float4 wv = *(const float4*)(wb + bidx);
        float4 bv = *(const float4*)(bias + bidx);
        bool vmask = (kt < 18) || (lg < 3);
        float p[4];
        #pragma unroll
        for (int r = 0; r < 4; ++r) {
            float x = a[r] * (&wv.x)[r] + (&bv.x)[r];
            p[r] = vmask ? __expf(gelu_exact(x)) : 0.f;
            ssum += p[r];
        }
        pk[kt][0] = (unsigned int)f2bf(p[0]) | ((unsigned int)f2bf(p[1]) << 16);
        pk[kt][1] = (unsigned int)f2bf(p[2]) | ((unsigned int)f2bf(p[3]) << 16);
    }
    pk[19][0] = 0; pk[19][1] = 0;   // keys 304+ don't exist

    // denominator across lg groups (all 4 copies per q-row become equal)
    ssum += __shfl_xor(ssum, 16);
    ssum += __shfl_xor(ssum, 32);
    float inv = 1.0f / ssum;

    // ---- PV: O[16q x 256v] per wave; P via shfl, V dbuf LDS (glds) ----
    f32x4 acc[16];
    #pragma unroll
    for (int nt = 0; nt < 16; ++nt) acc[nt] = (f32x4){0.f, 0.f, 0.f, 0.f};

    int s0 = lr + 32 * (lg & 1), s1 = s0 + 16;          // shfl source lanes
    bool hi = (lg >= 2);
    int rbase = lr * 32 + (lg ^ ((lr >> 1) & 3)) * 8;   // swizzled read base

    asm volatile("s_waitcnt vmcnt(0)" ::: "memory");
    __builtin_amdgcn_s_barrier();                       // chunk 0 ready
    asm volatile("" ::: "memory");

    #pragma unroll
    for (int kc = 0; kc < 10; ++kc) {
        // stage next chunk into the other buffer (hidden under MFMAs)
        if (kc < 9) {
            const ushort* nc = vchunk + (size_t)(kc + 1) * 8192;
            #pragma unroll
            for (int c = 0; c < 4; ++c)
                GLDS16(nc + w * 2048 + c * 512 + l * 8,
                       &Vs[(kc + 1) & 1][w * 2048 + c * 512]);
        }

        // pa = P[q=lr][kc*32 + lg*8 .. +7] via 8 shfl + 4 selects
        unsigned int e0 = __shfl((int)pk[2 * kc][0], s0);
        unsigned int e1 = __shfl((int)pk[2 * kc][1], s0);
        unsigned int o0 = __shfl((int)pk[2 * kc + 1][0], s0);
        unsigned int o1 = __shfl((int)pk[2 * kc + 1][1], s0);
        unsigned int E0 = __shfl((int)pk[2 * kc][0], s1);
        unsigned int E1 = __shfl((int)pk[2 * kc][1], s1);
        unsigned int O0 = __shfl((int)pk[2 * kc + 1][0], s1);
        unsigned int O1 = __shfl((int)pk[2 * kc + 1][1], s1);
        u32x4 pv;
        pv[0] = hi ? o0 : e0;
        pv[1] = hi ? o1 : e1;
        pv[2] = hi ? O0 : E0;
        pv[3] = hi ? O1 : E1;
        s16x8 pa = __builtin_bit_cast(s16x8, pv);

        const ushort* vsb = &Vs[kc & 1][0];
        #pragma unroll
        for (int nt = 0; nt < 16; ++nt) {
            s16x8 vb = *(const s16x8*)(vsb + rbase + nt * 512);
            acc[nt] = MFMA16(pa, vb, acc[nt]);
        }

        asm volatile("s_waitcnt vmcnt(0)" ::: "memory");  // next chunk landed
        __builtin_amdgcn_s_barrier();                     // all reads done too
        asm volatile("" ::: "memory");
    }

    // ---- normalize + store: q = qt*64 + w*16 + lg*4 + r, v = nt*16 + lr ----
    float invr[4];
    #pragma unroll
    for (int r = 0; r < 4; ++r) invr[r] = __shfl(inv, lg * 4 + r);
    #pragma unroll
    for (int nt = 0; nt < 16; ++nt)
        #pragma unroll
        for (int r = 0; r < 4; ++r) {
            int q = qt * 64 + w * 16 + lg * 4 + r;
            if (q < 300)
                O[((size_t)(b * 300 + q)) * 2048 + h * 256 + nt * 16 + lr] =
                    f2bf(acc[nt][r] * invr[r]);
        }
}

extern "C" void kernel_launch(void* const* d_in, const int* in_sizes, int n_in,
                              void* d_out, int out_size, void* d_ws, size_t ws_size,
                              hipStream_t stream) {
    const float* qf    = (const float*)d_in[0];
    const float* bias  = (const float*)d_in[1];
    const float* W_gen = (const float*)d_in[2];
    const float* b_gen = (const float*)d_in[3];
    const float* W_val = (const float*)d_in[4];
    const float* b_val = (const float*)d_in[5];
    const float* W_out = (const float*)d_in[6];
    const float* b_out = (const float*)d_in[7];
    const float* wb    = (const float*)d_in[8];
    float* out = (float*)d_out;

    char* ws = (char*)d_ws;
    ushort* qf_bf = (ushort*)(ws);                       // 19,660,800 B
    ushort* G_bf  = (ushort*)(ws + 19660800);            // 19,660,800 B
    ushort* Vt    = (ushort*)(ws + 39321600);            // 83,886,080 B (tiled+swz)
    ushort* O_bf  = (ushort*)(ws + 123207680);           // 78,643,200 B
    ushort* WgT   = (ushort*)(ws + 201850880);           //    524,288 B
    ushort* WvT   = (ushort*)(ws + 202375168);           //  2,097,152 B
    ushort* WoT   = (ushort*)(ws + 204472320);           //  2,097,152 B

    // stage 0: conversions / transposes / pad-zero
    k_cvt<<<dim3(9600), dim3(256), 0, stream>>>(qf, qf_bf, 9830400);
    k_twT<<<dim3(16, 16), dim3(256), 0, stream>>>(W_gen, WgT, 512, 512);
    k_twT<<<dim3(16, 64), dim3(256), 0, stream>>>(W_val, WvT, 512, 2048);
    k_twT<<<dim3(64, 16), dim3(256), 0, stream>>>(W_out, WoT, 2048, 512);
    k_zeroV9<<<dim3(2048), dim3(256), 0, stream>>>(Vt);

    // stage 1: G = qf@W_gen + b_gen ; V (tiled, swizzled) = (qf@W_val + b_val)
    k_gemm<0><<<dim3(152 * 4),  dim3(256), 0, stream>>>(qf_bf, WgT, b_gen, nullptr, G_bf, 512, 512, 4);
    k_gemm<1><<<dim3(152 * 16), dim3(256), 0, stream>>>(qf_bf, WvT, b_val, nullptr, Vt, 2048, 512, 16);

    // stage 2: fused attention
    k_attn<<<dim3(2560), dim3(256), 0, stream>>>(qf_bf, G_bf, Vt, wb, bias, O_bf);

    // stage 3: out = O @ W_out + b_out + qf
    k_gemm<2><<<dim3(152 * 4), dim3(256), 0, stream>>>(O_bf, WoT, b_out, qf, out, 512, 2048, 4);
}

// Round 8
// 417.942 us; speedup vs baseline: 1.2929x; 1.2929x over previous
//
#include <hip/hip_runtime.h>
#include <hip/hip_bf16.h>

typedef __attribute__((ext_vector_type(4))) float f32x4;
typedef __attribute__((ext_vector_type(8))) short s16x8;
typedef __attribute__((ext_vector_type(4))) short s16x4;

#define MFMA16(A, B, C) __builtin_amdgcn_mfma_f32_16x16x32_bf16((A), (B), (C), 0, 0, 0)

#define GLDS16(gsrc, ldst) __builtin_amdgcn_global_load_lds(                   \
    (const __attribute__((address_space(1))) void*)(gsrc),                    \
    (__attribute__((address_space(3))) void*)(ldst), 16, 0, 0)

__device__ __forceinline__ ushort f2bf(float f) {
    __hip_bfloat16 h = __float2bfloat16(f);
    return *reinterpret_cast<ushort*>(&h);
}

// branchless exact GELU via Abramowitz-Stegun 7.1.26 erf (|err| <= 1.5e-7)
__device__ __forceinline__ float gelu_exact(float x) {
    float z = 0.70710678118f * x;
    float az = fabsf(z);
    float t = 1.0f / fmaf(0.3275911f, az, 1.0f);
    float poly = t * (0.254829592f + t * (-0.284496736f + t * (1.421413741f +
                 t * (-1.453152027f + t * 1.061405429f))));
    float e = __expf(-az * az);
    float erfv = copysignf(1.0f - poly * e, z);
    return 0.5f * x * (1.0f + erfv);
}

// ---------------- convert fp32 -> bf16 (vectorized x4) ----------------
__global__ void k_cvt(const float* __restrict__ in, ushort* __restrict__ out, int n) {
    int i = (blockIdx.x * 256 + threadIdx.x) * 4;
    if (i + 3 >= n) return;
    float4 v = *(const float4*)(in + i);
    ushort4 o;
    o.x = f2bf(v.x); o.y = f2bf(v.y); o.z = f2bf(v.z); o.w = f2bf(v.w);
    *(ushort4*)(out + i) = o;
}

// ---------------- transpose weight [K,N] f32 -> [N,K] bf16 ----------------
__global__ void k_twT(const float* __restrict__ w, ushort* __restrict__ wt, int K, int N) {
    __shared__ float tile[32][33];
    int k0 = blockIdx.x * 32, n0 = blockIdx.y * 32;
    int tx = threadIdx.x & 31, ty = threadIdx.x >> 5;   // 32 x 8
    #pragma unroll
    for (int i = ty; i < 32; i += 8)
        tile[i][tx] = w[(size_t)(k0 + i) * N + n0 + tx];
    __syncthreads();
    #pragma unroll
    for (int i = ty; i < 32; i += 8)
        wt[(size_t)(n0 + i) * K + k0 + tx] = f2bf(tile[tx][i]);
}

// ---------------- zero chunk 9 of Vt (keys 288..319 region) ----------------
// Vt tiled layout: [(b*8+h)][kc(10)][v(256)][k32(32)] ushort (slot-swizzled)
__global__ void k_zeroV9(ushort* __restrict__ Vt) {
    int i = (blockIdx.x * 256 + threadIdx.x) * 8;   // < 512*8192
    int bh = i >> 13, within = i & 8191;
    s16x8 z = {0, 0, 0, 0, 0, 0, 0, 0};
    *(s16x8*)(Vt + ((size_t)bh * 10 + 9) * 8192 + within) = z;
}

// ---------------- GEMM: A[M,K]bf16 @ BT[N,K]bf16^T + bias ----------------
// m97 structure: global_load_lds width-16 staging, linear LDS [128][32].
// Grid: 1D, 152*GY blocks (GX=150 padded to 152=19*8 for XCD chunking).
// OUT=0: bf16 [M,N].  OUT=1: bf16 tiled+swizzled Vt.  OUT=2: f32 +bias+resid.
template <int OUT>
__global__ __launch_bounds__(256) void k_gemm(const ushort* __restrict__ A,
                                              const ushort* __restrict__ BT,
                                              const float* __restrict__ bias,
                                              const float* __restrict__ resid,
                                              void* __restrict__ outp,
                                              int N, int K, int GY) {
    __shared__ __align__(16) ushort As[128][32];
    __shared__ __align__(16) ushort Bs[128][32];
    int id = blockIdx.x;
    int xcd = id & 7, s = id >> 3;          // s in [0, 19*GY)
    int mxl = s / GY, ny = s - mxl * GY;
    int mx = xcd * 19 + mxl;
    if (mx >= 150) return;
    int m0 = mx * 128, n0 = ny * 128;

    int t = threadIdx.x, l = t & 63, w = t >> 6;
    int wm = (w >> 1) * 64, wn = (w & 1) * 64;
    int lr = l & 15, lg = l >> 4;
    ushort* AsF = &As[0][0];
    ushort* BsF = &Bs[0][0];

    f32x4 acc[4][4];
    #pragma unroll
    for (int i = 0; i < 4; ++i)
        #pragma unroll
        for (int j = 0; j < 4; ++j)
            acc[i][j] = (f32x4){0.f, 0.f, 0.f, 0.f};

    for (int k0 = 0; k0 < K; k0 += 32) {
        #pragma unroll
        for (int c = 0; c < 2; ++c) {
            int cb = w * 128 + c * 64;          // wave-uniform chunk base
            int ch = cb + l;
            int row = ch >> 2, col = (ch & 3) * 8;
            GLDS16(A + (size_t)(m0 + row) * K + k0 + col, AsF + (size_t)cb * 8);
            GLDS16(BT + (size_t)(n0 + row) * K + k0 + col, BsF + (size_t)cb * 8);
        }
        __syncthreads();
        s16x8 af[4], bfr[4];
        #pragma unroll
        for (int i = 0; i < 4; ++i) af[i] = *(const s16x8*)(&As[wm + i * 16 + lr][lg * 8]);
        #pragma unroll
        for (int j = 0; j < 4; ++j) bfr[j] = *(const s16x8*)(&Bs[wn + j * 16 + lr][lg * 8]);
        #pragma unroll
        for (int i = 0; i < 4; ++i)
            #pragma unroll
            for (int j = 0; j < 4; ++j)
                acc[i][j] = MFMA16(af[i], bfr[j], acc[i][j]);
        __syncthreads();
    }

    if (OUT == 0) {
        ushort* out = (ushort*)outp;
        #pragma unroll
        for (int i = 0; i < 4; ++i)
            #pragma unroll
            for (int j = 0; j < 4; ++j) {
                int col = n0 + wn + j * 16 + lr;
                float bv = bias[col];
                #pragma unroll
                for (int r = 0; r < 4; ++r) {
                    int row = m0 + wm + i * 16 + lg * 4 + r;
                    out[(size_t)row * N + col] = f2bf(acc[i][j][r] + bv);
                }
            }
    } else if (OUT == 1) {
        ushort* Vt = (ushort*)outp;
        #pragma unroll
        for (int i = 0; i < 4; ++i)
            #pragma unroll
            for (int j = 0; j < 4; ++j) {
                int col = n0 + wn + j * 16 + lr;
                float bv = bias[col];
                int hh = col >> 8, v = col & 255;
                #pragma unroll
                for (int r = 0; r < 4; ++r) {
                    int row = m0 + wm + i * 16 + lg * 4 + r;
                    int bb = row / 300, key = row - bb * 300;
                    int ck = key >> 5, kk = key & 31;
                    int sl = (kk >> 3) ^ ((v >> 1) & 3);    // 16B-slot swizzle
                    size_t addr = (((size_t)(bb * 8 + hh) * 10 + ck) * 8192)
                                  + v * 32 + sl * 8 + (kk & 7);
                    Vt[addr] = f2bf(acc[i][j][r] + bv);
                }
            }
    } else {
        float* out = (float*)outp;
        #pragma unroll
        for (int i = 0; i < 4; ++i)
            #pragma unroll
            for (int j = 0; j < 4; ++j) {
                int col = n0 + wn + j * 16 + lr;
                float bv = bias[col];
                #pragma unroll
                for (int r = 0; r < 4; ++r) {
                    int row = m0 + wm + i * 16 + lg * 4 + r;
                    size_t idx = (size_t)row * N + col;
                    out[idx] = acc[i][j][r] + bv + resid[idx];
                }
            }
    }
}

// ---------------- fused attention ----------------
// Streaming no-max softmax (scores ~N(0,1.1): exp safe in f32; shift-invariant).
// P (unnormalized exp, bf16) streamed to LDS with a (q&15)<<4 XOR swizzle
// (<=2-way banks). 1/sum folded into PV epilogue. Regs capped at 128 (no pk,
// no sc arrays -> no spill). V double-buffered via global_load_lds.
__global__ __launch_bounds__(256, 4) void k_attn(const ushort* __restrict__ qf_bf,
                                                 const ushort* __restrict__ G_bf,
                                                 const ushort* __restrict__ Vt,
                                                 const float* __restrict__ wb,
                                                 const float* __restrict__ bias,
                                                 ushort* __restrict__ O) {
    __shared__ __align__(16) ushort P[64 * 320];   // 40,960 B swizzled
    __shared__ __align__(16) ushort Vs[2][8192];   // 32,768 B
    int id = blockIdx.x;
    int xcd = id & 7, s = id >> 3;        // s in [0,320)
    int h = s / 40; int r2 = s - h * 40;
    int bi = r2 / 5, qt = r2 - bi * 5;
    int b = xcd * 8 + bi;

    int t = threadIdx.x, l = t & 63, w = t >> 6;
    int lr = l & 15, lg = l >> 4;

    // swizzled P address: q in [0,64), k in [0,320); preserves 8B alignment
    auto p_addr = [&](int q, int k) -> ushort* {
        int byte = (q * 640 + k * 2) ^ ((q & 15) << 4);
        return (ushort*)((char*)P + byte);
    };

    const ushort* vchunk = Vt + (size_t)(b * 8 + h) * 81920;   // 10 x 8192

    // stage chunk 0 (async, no VGPRs) -- lands during scores phase
    #pragma unroll
    for (int c = 0; c < 4; ++c)
        GLDS16(vchunk + w * 2048 + c * 512 + l * 8, &Vs[0][w * 2048 + c * 512]);

    // Q fragment (B operand): col = q = lane&15
    int qr = min(qt * 64 + w * 16 + lr, 299);
    const ushort* qp = qf_bf + ((size_t)(b * 300 + qr)) * 512 + h * 64 + lg * 8;
    s16x8 q0 = *(const s16x8*)(qp);
    s16x8 q1 = *(const s16x8*)(qp + 32);

    // ---- scores^T streamed: gelu -> exp -> pack -> P LDS write ----
    int qq = w * 16 + lr;
    float ssum = 0.f;
    #pragma unroll
    for (int kt = 0; kt < 19; ++kt) {
        int key = kt * 16 + lr;
        int kcl = min(key, 299);
        const ushort* gp = G_bf + ((size_t)(b * 300 + kcl)) * 512 + h * 64 + lg * 8;
        s16x8 g0 = *(const s16x8*)(gp);
        s16x8 g1 = *(const s16x8*)(gp + 32);
        f32x4 a = (f32x4){0.f, 0.f, 0.f, 0.f};
        a = MFMA16(g0, q0, a);
        a = MFMA16(g1, q1, a);
        int k0 = kt * 16 + lg * 4;
        int k0c = min(k0, 296);
        size_t bidx = ((size_t)h * 300 + qr) * 300 + k0c;
        float4 wv = *(const float4*)(wb + bidx);
        float4 bv = *(const float4*)(bias + bidx);
        bool vmask = (kt < 18) || (lg < 3);
        s16x4 pw;
        #pragma unroll
        for (int r = 0; r < 4; ++r) {
            float x = a[r] * (&wv.x)[r] + (&bv.x)[r];
            float p = vmask ? __expf(gelu_exact(x)) : 0.f;
            ssum += p;
            pw[r] = (short)f2bf(p);
        }
        *(s16x4*)p_addr(qq, k0) = pw;
    }
    // zero pad keys 304..319 (64 rows x 16 keys; one s16x4 per thread)
    *(s16x4*)p_addr(t >> 2, 304 + (t & 3) * 4) = (s16x4){0, 0, 0, 0};

    // denominator across lg groups (4 copies per q-row become equal)
    ssum += __shfl_xor(ssum, 16);
    ssum += __shfl_xor(ssum, 32);
    float inv = 1.0f / ssum;

    __syncthreads();   // P visible; chunk 0 (vmcnt) drained

    // ---- PV: O[16q x 256v] per wave; pa from P LDS, V dbuf (glds) ----
    f32x4 acc[16];
    #pragma unroll
    for (int nt = 0; nt < 16; ++nt) acc[nt] = (f32x4){0.f, 0.f, 0.f, 0.f};

    int rbase = lr * 32 + (lg ^ ((lr >> 1) & 3)) * 8;   // swizzled V read base

    #pragma unroll
    for (int kc = 0; kc < 10; ++kc) {
        // stage next chunk into the other buffer (hidden under MFMAs)
        if (kc < 9) {
            const ushort* nc = vchunk + (size_t)(kc + 1) * 8192;
            #pragma unroll
            for (int c = 0; c < 4; ++c)
                GLDS16(nc + w * 2048 + c * 512 + l * 8,
                       &Vs[(kc + 1) & 1][w * 2048 + c * 512]);
        }

        s16x8 pa = *(const s16x8*)p_addr(qq, kc * 32 + lg * 8);
        const ushort* vsb = &Vs[kc & 1][0];
        #pragma unroll
        for (int nt = 0; nt < 16; ++nt) {
            s16x8 vb = *(const s16x8*)(vsb + rbase + nt * 512);
            acc[nt] = MFMA16(pa, vb, acc[nt]);
        }

        asm volatile("s_waitcnt vmcnt(0)" ::: "memory");  // next chunk landed
        __builtin_amdgcn_s_barrier();                     // all reads done too
        asm volatile("" ::: "memory");
    }

    // ---- normalize + store: q = qt*64 + w*16 + lg*4 + r, v = nt*16 + lr ----
    float invr[4];
    #pragma unroll
    for (int r = 0; r < 4; ++r) invr[r] = __shfl(inv, lg * 4 + r);
    #pragma unroll
    for (int nt = 0; nt < 16; ++nt)
        #pragma unroll
        for (int r = 0; r < 4; ++r) {
            int q = qt * 64 + w * 16 + lg * 4 + r;
            if (q < 300)
                O[((size_t)(b * 300 + q)) * 2048 + h * 256 + nt * 16 + lr] =
                    f2bf(acc[nt][r] * invr[r]);
        }
}

extern "C" void kernel_launch(void* const* d_in, const int* in_sizes, int n_in,
                              void* d_out, int out_size, void* d_ws, size_t ws_size,
                              hipStream_t stream) {
    const float* qf    = (const float*)d_in[0];
    const float* bias  = (const float*)d_in[1];
    const float* W_gen = (const float*)d_in[2];
    const float* b_gen = (const float*)d_in[3];
    const float* W_val = (const float*)d_in[4];
    const float* b_val = (const float*)d_in[5];
    const float* W_out = (const float*)d_in[6];
    const float* b_out = (const float*)d_in[7];
    const float* wb    = (const float*)d_in[8];
    float* out = (float*)d_out;

    char* ws = (char*)d_ws;
    ushort* qf_bf = (ushort*)(ws);                       // 19,660,800 B
    ushort* G_bf  = (ushort*)(ws + 19660800);            // 19,660,800 B
    ushort* Vt    = (ushort*)(ws + 39321600);            // 83,886,080 B (tiled+swz)
    ushort* O_bf  = (ushort*)(ws + 123207680);           // 78,643,200 B
    ushort* WgT   = (ushort*)(ws + 201850880);           //    524,288 B
    ushort* WvT   = (ushort*)(ws + 202375168);           //  2,097,152 B
    ushort* WoT   = (ushort*)(ws + 204472320);           //  2,097,152 B

    // stage 0: conversions / transposes / pad-zero
    k_cvt<<<dim3(9600), dim3(256), 0, stream>>>(qf, qf_bf, 9830400);
    k_twT<<<dim3(16, 16), dim3(256), 0, stream>>>(W_gen, WgT, 512, 512);
    k_twT<<<dim3(16, 64), dim3(256), 0, stream>>>(W_val, WvT, 512, 2048);
    k_twT<<<dim3(64, 16), dim3(256), 0, stream>>>(W_out, WoT, 2048, 512);
    k_zeroV9<<<dim3(2048), dim3(256), 0, stream>>>(Vt);

    // stage 1: G = qf@W_gen + b_gen ; V (tiled, swizzled) = (qf@W_val + b_val)
    k_gemm<0><<<dim3(152 * 4),  dim3(256), 0, stream>>>(qf_bf, WgT, b_gen, nullptr, G_bf, 512, 512, 4);
    k_gemm<1><<<dim3(152 * 16), dim3(256), 0, stream>>>(qf_bf, WvT, b_val, nullptr, Vt, 2048, 512, 16);

    // stage 2: fused attention
    k_attn<<<dim3(2560), dim3(256), 0, stream>>>(qf_bf, G_bf, Vt, wb, bias, O_bf);

    // stage 3: out = O @ W_out + b_out + qf
    k_gemm<2><<<dim3(152 * 4), dim3(256), 0, stream>>>(O_bf, WoT, b_out, qf, out, 512, 2048, 4);
}

// Round 9
// 377.800 us; speedup vs baseline: 1.4302x; 1.1063x over previous
//
#include <hip/hip_runtime.h>
#include <hip/hip_bf16.h>

typedef __attribute__((ext_vector_type(4))) float f32x4;
typedef __attribute__((ext_vector_type(8))) short s16x8;
typedef __attribute__((ext_vector_type(4))) short s16x4;

#define MFMA16(A, B, C) __builtin_amdgcn_mfma_f32_16x16x32_bf16((A), (B), (C), 0, 0, 0)

#define GLDS16(gsrc, ldst) __builtin_amdgcn_global_load_lds(                   \
    (const __attribute__((address_space(1))) void*)(gsrc),                    \
    (__attribute__((address_space(3))) void*)(ldst), 16, 0, 0)

__device__ __forceinline__ ushort f2bf(float f) {
    __hip_bfloat16 h = __float2bfloat16(f);
    return *reinterpret_cast<ushort*>(&h);
}

// branchless exact GELU via Abramowitz-Stegun 7.1.26 erf (|err| <= 1.5e-7)
__device__ __forceinline__ float gelu_exact(float x) {
    float z = 0.70710678118f * x;
    float az = fabsf(z);
    float t = 1.0f / fmaf(0.3275911f, az, 1.0f);
    float poly = t * (0.254829592f + t * (-0.284496736f + t * (1.421413741f +
                 t * (-1.453152027f + t * 1.061405429f))));
    float e = __expf(-az * az);
    float erfv = copysignf(1.0f - poly * e, z);
    return 0.5f * x * (1.0f + erfv);
}

// ---------------- convert fp32 -> bf16 (vectorized x4) ----------------
__global__ void k_cvt(const float* __restrict__ in, ushort* __restrict__ out, int n) {
    int i = (blockIdx.x * 256 + threadIdx.x) * 4;
    if (i + 3 >= n) return;
    float4 v = *(const float4*)(in + i);
    ushort4 o;
    o.x = f2bf(v.x); o.y = f2bf(v.y); o.z = f2bf(v.z); o.w = f2bf(v.w);
    *(ushort4*)(out + i) = o;
}

// ---------------- transpose weight [K,N] f32 -> [N,K] bf16 ----------------
__global__ void k_twT(const float* __restrict__ w, ushort* __restrict__ wt, int K, int N) {
    __shared__ float tile[32][33];
    int k0 = blockIdx.x * 32, n0 = blockIdx.y * 32;
    int tx = threadIdx.x & 31, ty = threadIdx.x >> 5;   // 32 x 8
    #pragma unroll
    for (int i = ty; i < 32; i += 8)
        tile[i][tx] = w[(size_t)(k0 + i) * N + n0 + tx];
    __syncthreads();
    #pragma unroll
    for (int i = ty; i < 32; i += 8)
        wt[(size_t)(n0 + i) * K + k0 + tx] = f2bf(tile[tx][i]);
}

// ---------------- zero chunk 9 of Vt (keys 288..319 region) ----------------
// Vt tiled layout: [(b*8+h)][kc(10)][v(256)][k32(32)] ushort
__global__ void k_zeroV9(ushort* __restrict__ Vt) {
    int i = (blockIdx.x * 256 + threadIdx.x) * 8;   // < 512*8192
    int bh = i >> 13, within = i & 8191;
    s16x8 z = {0, 0, 0, 0, 0, 0, 0, 0};
    *(s16x8*)(Vt + ((size_t)bh * 10 + 9) * 8192 + within) = z;
}

// ---------------- GEMM: A[M,K]bf16 @ BT[N,K]bf16^T + bias ----------------
// T3-min 2-phase: dbuf LDS, stage(t+1) BEFORE compute(t), one vmcnt(0)+barrier
// per K-step (staging hides under MFMAs). global_load_lds width-16.
// Grid: 1D, 152*GY blocks (GX=150 padded to 152=19*8 for XCD chunking).
// OUT=0: bf16 [M,N].  OUT=1: bf16 tiled Vt.  OUT=2: f32 +bias+resid.
template <int OUT>
__global__ __launch_bounds__(256) void k_gemm(const ushort* __restrict__ A,
                                              const ushort* __restrict__ BT,
                                              const float* __restrict__ bias,
                                              const float* __restrict__ resid,
                                              void* __restrict__ outp,
                                              int N, int K, int GY) {
    __shared__ __align__(16) ushort As[2][128][32];
    __shared__ __align__(16) ushort Bs[2][128][32];
    int id = blockIdx.x;
    int xcd = id & 7, s = id >> 3;          // s in [0, 19*GY)
    int mxl = s / GY, ny = s - mxl * GY;
    int mx = xcd * 19 + mxl;
    if (mx >= 150) return;
    int m0 = mx * 128, n0 = ny * 128;

    int t = threadIdx.x, l = t & 63, w = t >> 6;
    int wm = (w >> 1) * 64, wn = (w & 1) * 64;
    int lr = l & 15, lg = l >> 4;

    auto stage = [&](int it, int buf) {
        ushort* AsF = &As[buf][0][0];
        ushort* BsF = &Bs[buf][0][0];
        int k0 = it * 32;
        #pragma unroll
        for (int c = 0; c < 2; ++c) {
            int cb = w * 128 + c * 64;          // wave-uniform chunk base
            int ch = cb + l;
            int row = ch >> 2, col = (ch & 3) * 8;
            GLDS16(A + (size_t)(m0 + row) * K + k0 + col, AsF + (size_t)cb * 8);
            GLDS16(BT + (size_t)(n0 + row) * K + k0 + col, BsF + (size_t)cb * 8);
        }
    };

    f32x4 acc[4][4];
    #pragma unroll
    for (int i = 0; i < 4; ++i)
        #pragma unroll
        for (int j = 0; j < 4; ++j)
            acc[i][j] = (f32x4){0.f, 0.f, 0.f, 0.f};

    stage(0, 0);
    asm volatile("s_waitcnt vmcnt(0)" ::: "memory");
    __builtin_amdgcn_s_barrier();

    int nit = K >> 5;
    for (int it = 0; it < nit; ++it) {
        int cur = it & 1;
        if (it + 1 < nit) stage(it + 1, cur ^ 1);   // prefetch next tile
        s16x8 af[4], bfr[4];
        #pragma unroll
        for (int i = 0; i < 4; ++i) af[i] = *(const s16x8*)(&As[cur][wm + i * 16 + lr][lg * 8]);
        #pragma unroll
        for (int j = 0; j < 4; ++j) bfr[j] = *(const s16x8*)(&Bs[cur][wn + j * 16 + lr][lg * 8]);
        #pragma unroll
        for (int i = 0; i < 4; ++i)
            #pragma unroll
            for (int j = 0; j < 4; ++j)
                acc[i][j] = MFMA16(af[i], bfr[j], acc[i][j]);
        asm volatile("s_waitcnt vmcnt(0)" ::: "memory");  // next tile landed
        __builtin_amdgcn_s_barrier();
    }

    if (OUT == 0) {
        ushort* out = (ushort*)outp;
        #pragma unroll
        for (int i = 0; i < 4; ++i)
            #pragma unroll
            for (int j = 0; j < 4; ++j) {
                int col = n0 + wn + j * 16 + lr;
                float bv = bias[col];
                #pragma unroll
                for (int r = 0; r < 4; ++r) {
                    int row = m0 + wm + i * 16 + lg * 4 + r;
                    out[(size_t)row * N + col] = f2bf(acc[i][j][r] + bv);
                }
            }
    } else if (OUT == 1) {
        ushort* Vt = (ushort*)outp;
        #pragma unroll
        for (int i = 0; i < 4; ++i)
            #pragma unroll
            for (int j = 0; j < 4; ++j) {
                int col = n0 + wn + j * 16 + lr;
                float bv = bias[col];
                int hh = col >> 8, v = col & 255;
                #pragma unroll
                for (int r = 0; r < 4; ++r) {
                    int row = m0 + wm + i * 16 + lg * 4 + r;
                    int bb = row / 300, key = row - bb * 300;
                    size_t addr = (((size_t)(bb * 8 + hh) * 10 + (key >> 5)) * 8192)
                                  + v * 32 + (key & 31);
                    Vt[addr] = f2bf(acc[i][j][r] + bv);
                }
            }
    } else {
        float* out = (float*)outp;
        #pragma unroll
        for (int i = 0; i < 4; ++i)
            #pragma unroll
            for (int j = 0; j < 4; ++j) {
                int col = n0 + wn + j * 16 + lr;
                float bv = bias[col];
                #pragma unroll
                for (int r = 0; r < 4; ++r) {
                    int row = m0 + wm + i * 16 + lg * 4 + r;
                    size_t idx = (size_t)row * N + col;
                    out[idx] = acc[i][j][r] + bv + resid[idx];
                }
            }
    }
}

// ---------------- fused attention ----------------
// Scores: per-wave private P rows (streamed no-max exp, bf16, XOR-swizzled LDS).
// PV: waves split by v-range (wave w owns v in [w*64, w*64+64) for ALL 64 q)
// -> V slice read ONCE per block straight from L2, no Vs staging, ONE barrier.
// LDS = P (40,960) + invL (256) -> 3 blocks/CU; regs capped at 128.
__global__ __launch_bounds__(256, 4) void k_attn(const ushort* __restrict__ qf_bf,
                                                 const ushort* __restrict__ G_bf,
                                                 const ushort* __restrict__ Vt,
                                                 const float* __restrict__ wb,
                                                 const float* __restrict__ bias,
                                                 ushort* __restrict__ O) {
    __shared__ __align__(16) ushort P[64 * 320];   // 40,960 B swizzled
    __shared__ float invL[64];
    int id = blockIdx.x;
    int xcd = id & 7, s = id >> 3;        // s in [0,320)
    int h = s / 40; int r2 = s - h * 40;
    int bi = r2 / 5, qt = r2 - bi * 5;
    int b = xcd * 8 + bi;

    int t = threadIdx.x, l = t & 63, w = t >> 6;
    int lr = l & 15, lg = l >> 4;

    // swizzled P address: q in [0,64), k in [0,320); preserves 8B alignment
    auto p_addr = [&](int q, int k) -> ushort* {
        int byte = (q * 640 + k * 2) ^ ((q & 15) << 4);
        return (ushort*)((char*)P + byte);
    };

    // Q fragment (B operand): col = q = lane&15
    int qr = min(qt * 64 + w * 16 + lr, 299);
    const ushort* qp = qf_bf + ((size_t)(b * 300 + qr)) * 512 + h * 64 + lg * 8;
    s16x8 q0 = *(const s16x8*)(qp);
    s16x8 q1 = *(const s16x8*)(qp + 32);

    // ---- scores^T streamed: gelu -> exp -> pack -> P LDS write ----
    int qq = w * 16 + lr;
    float ssum = 0.f;
    #pragma unroll
    for (int kt = 0; kt < 19; ++kt) {
        int key = kt * 16 + lr;
        int kcl = min(key, 299);
        const ushort* gp = G_bf + ((size_t)(b * 300 + kcl)) * 512 + h * 64 + lg * 8;
        s16x8 g0 = *(const s16x8*)(gp);
        s16x8 g1 = *(const s16x8*)(gp + 32);
        f32x4 a = (f32x4){0.f, 0.f, 0.f, 0.f};
        a = MFMA16(g0, q0, a);
        a = MFMA16(g1, q1, a);
        int k0 = kt * 16 + lg * 4;
        int k0c = min(k0, 296);
        size_t bidx = ((size_t)h * 300 + qr) * 300 + k0c;
        float4 wv = *(const float4*)(wb + bidx);
        float4 bv = *(const float4*)(bias + bidx);
        bool vmask = (kt < 18) || (lg < 3);
        s16x4 pw;
        #pragma unroll
        for (int r = 0; r < 4; ++r) {
            float x = a[r] * (&wv.x)[r] + (&bv.x)[r];
            float p = vmask ? __expf(gelu_exact(x)) : 0.f;
            ssum += p;
            pw[r] = (short)f2bf(p);
        }
        *(s16x4*)p_addr(qq, k0) = pw;
    }
    // zero pad keys 304..319 -- per-wave rows only (no cross-wave writes)
    *(s16x4*)p_addr(w * 16 + (l >> 2), 304 + (l & 3) * 4) = (s16x4){0, 0, 0, 0};

    // denominator across lg groups; publish per-row 1/sum
    ssum += __shfl_xor(ssum, 16);
    ssum += __shfl_xor(ssum, 32);
    if (lg == 0) invL[qq] = 1.0f / ssum;

    __syncthreads();   // the ONLY barrier: P + invL visible to all waves

    // ---- PV: wave w owns v in [w*64, w*64+64) for all 64 q ----
    f32x4 acc[4][4];   // [qg][nt]
    #pragma unroll
    for (int qg = 0; qg < 4; ++qg)
        #pragma unroll
        for (int nt = 0; nt < 4; ++nt)
            acc[qg][nt] = (f32x4){0.f, 0.f, 0.f, 0.f};

    const ushort* vbase = Vt + (size_t)(b * 8 + h) * 81920
                          + (size_t)(w * 64) * 32 + lg * 8;
    #pragma unroll
    for (int kc = 0; kc < 10; ++kc) {
        s16x8 vb[4], pa[4];
        #pragma unroll
        for (int nt = 0; nt < 4; ++nt)
            vb[nt] = *(const s16x8*)(vbase + (size_t)kc * 8192 + (nt * 16 + lr) * 32);
        #pragma unroll
        for (int qg = 0; qg < 4; ++qg)
            pa[qg] = *(const s16x8*)p_addr(qg * 16 + lr, kc * 32 + lg * 8);
        #pragma unroll
        for (int qg = 0; qg < 4; ++qg)
            #pragma unroll
            for (int nt = 0; nt < 4; ++nt)
                acc[qg][nt] = MFMA16(pa[qg], vb[nt], acc[qg][nt]);
    }

    // ---- normalize + store: q = qt*64 + qg*16 + lg*4 + r, v = w*64 + nt*16 + lr
    #pragma unroll
    for (int qg = 0; qg < 4; ++qg)
        #pragma unroll
        for (int r = 0; r < 4; ++r) {
            int qloc = qg * 16 + lg * 4 + r;
            int q = qt * 64 + qloc;
            if (q < 300) {
                float iv = invL[qloc];
                #pragma unroll
                for (int nt = 0; nt < 4; ++nt) {
                    int v = w * 64 + nt * 16 + lr;
                    O[((size_t)(b * 300 + q)) * 2048 + h * 256 + v] =
                        f2bf(acc[qg][nt][r] * iv);
                }
            }
        }
}

extern "C" void kernel_launch(void* const* d_in, const int* in_sizes, int n_in,
                              void* d_out, int out_size, void* d_ws, size_t ws_size,
                              hipStream_t stream) {
    const float* qf    = (const float*)d_in[0];
    const float* bias  = (const float*)d_in[1];
    const float* W_gen = (const float*)d_in[2];
    const float* b_gen = (const float*)d_in[3];
    const float* W_val = (const float*)d_in[4];
    const float* b_val = (const float*)d_in[5];
    const float* W_out = (const float*)d_in[6];
    const float* b_out = (const float*)d_in[7];
    const float* wb    = (const float*)d_in[8];
    float* out = (float*)d_out;

    char* ws = (char*)d_ws;
    ushort* qf_bf = (ushort*)(ws);                       // 19,660,800 B
    ushort* G_bf  = (ushort*)(ws + 19660800);            // 19,660,800 B
    ushort* Vt    = (ushort*)(ws + 39321600);            // 83,886,080 B (tiled)
    ushort* O_bf  = (ushort*)(ws + 123207680);           // 78,643,200 B
    ushort* WgT   = (ushort*)(ws + 201850880);           //    524,288 B
    ushort* WvT   = (ushort*)(ws + 202375168);           //  2,097,152 B
    ushort* WoT   = (ushort*)(ws + 204472320);           //  2,097,152 B

    // stage 0: conversions / transposes / pad-zero
    k_cvt<<<dim3(9600), dim3(256), 0, stream>>>(qf, qf_bf, 9830400);
    k_twT<<<dim3(16, 16), dim3(256), 0, stream>>>(W_gen, WgT, 512, 512);
    k_twT<<<dim3(16, 64), dim3(256), 0, stream>>>(W_val, WvT, 512, 2048);
    k_twT<<<dim3(64, 16), dim3(256), 0, stream>>>(W_out, WoT, 2048, 512);
    k_zeroV9<<<dim3(2048), dim3(256), 0, stream>>>(Vt);

    // stage 1: G = qf@W_gen + b_gen ; V (tiled) = (qf@W_val + b_val)
    k_gemm<0><<<dim3(152 * 4),  dim3(256), 0, stream>>>(qf_bf, WgT, b_gen, nullptr, G_bf, 512, 512, 4);
    k_gemm<1><<<dim3(152 * 16), dim3(256), 0, stream>>>(qf_bf, WvT, b_val, nullptr, Vt, 2048, 512, 16);

    // stage 2: fused attention
    k_attn<<<dim3(2560), dim3(256), 0, stream>>>(qf_bf, G_bf, Vt, wb, bias, O_bf);

    // stage 3: out = O @ W_out + b_out + qf
    k_gemm<2><<<dim3(152 * 4), dim3(256), 0, stream>>>(O_bf, WoT, b_out, qf, out, 512, 2048, 4);
}